// Round 13
// baseline (247.461 us; speedup 1.0000x reference)
//
#include <hip/hip_runtime.h>
#include <hip/hip_bf16.h>
#include <hip/hip_cooperative_groups.h>

namespace cg = cooperative_groups;

#define BB 32
#define CC 128
#define OO 128
#define HH 56
#define WW 56
#define KK 4
#define HW 3136
#define WPLANE 147456
#define EPSV 1e-5f

#define NPOS 348                  // 6 rows x 58 cols staged positions
#define BUFB 22528                // bytes per LDS buffer = 1408 units x 16B (incl pad)

typedef __attribute__((ext_vector_type(8))) short short8v;
typedef __attribute__((ext_vector_type(4))) float f32x4;

static __device__ __forceinline__ void gload16(const void* g, void* l) {
    __builtin_amdgcn_global_load_lds((const __attribute__((address_space(1))) void*)g,
                                     (__attribute__((address_space(3))) void*)l, 16, 0, 0);
}

// ---- convert x -> bf16 channel-last [b][h][w][c], + per-(b,h,c) row sums ----
__global__ void convert_pool_kernel(const float* __restrict__ x,
                                    ushort* __restrict__ xbf,
                                    float* __restrict__ pooledp,
                                    ushort* __restrict__ zpage) {
    const int h = blockIdx.x, b = blockIdx.y;
    if (h == 0 && b == 0 && threadIdx.x < 32) zpage[threadIdx.x] = 0;
    __shared__ float4 xl4[1792];               // [c][w4] swizzled, 28672 B
    const float* xp = x + (size_t)(b * CC) * HW + h * WW;

    #pragma unroll
    for (int k = 0; k < 7; ++k) {
        int u = threadIdx.x + k * 256;
        int c = u / 14, w4 = u - c * 14;
        float4 v = *(const float4*)(xp + (size_t)c * HW + w4 * 4);
        xl4[u ^ ((c >> 3) & 7)] = v;
    }
    __syncthreads();

    const float* xf = (const float*)xl4;
    #pragma unroll
    for (int k = 0; k < 4; ++k) {
        int v = threadIdx.x + k * 256;
        if (v < 896) {
            int w = v >> 4, c8 = v & 15;
            int w4 = w >> 2, wo = w & 3;
            short8v res;
            #pragma unroll
            for (int j = 0; j < 8; ++j) {
                int c = c8 * 8 + j;
                int su = (c * 14 + w4) ^ (c8 & 7);
                __hip_bfloat16 hb = __float2bfloat16(xf[su * 4 + wo]);
                res[j] = *(short*)&hb;
            }
            *(short8v*)(xbf + ((size_t)((b * HH + h) * WW + w)) * CC + c8 * 8) = res;
        }
    }

    if (threadIdx.x < 128) {
        int c = threadIdx.x;
        float s = 0.f;
        #pragma unroll
        for (int w4 = 0; w4 < 14; ++w4) {
            float4 v = xl4[(c * 14 + w4) ^ ((c >> 3) & 7)];
            s += v.x + v.y + v.z + v.w;
        }
        pooledp[((size_t)(b * HH + h)) * CC + c] = s;
    }
}

// ---- attention: reduce pooled partials + tiny MLP + softmax. block per b ----
__global__ void attn_kernel(const float* __restrict__ pooledp,
                            const float* __restrict__ fc1_w, const float* __restrict__ fc1_b,
                            const float* __restrict__ fc2_w, const float* __restrict__ fc2_b,
                            float* __restrict__ attn) {
    const int b = blockIdx.x, c = threadIdx.x;      // 128 threads
    float s = 0.f;
    for (int h = 0; h < HH; ++h) s += pooledp[((size_t)(b * HH + h)) * CC + c];
    const float pc = s * (1.0f / HW);
    __shared__ float red[8];
    const int lane = c & 63, wid = c >> 6;
    #pragma unroll
    for (int k = 0; k < KK; ++k) {
        float v = pc * fc1_w[k * CC + c];
        for (int off = 32; off > 0; off >>= 1) v += __shfl_down(v, off, 64);
        if (lane == 0) red[k * 2 + wid] = v;
    }
    __syncthreads();
    if (c == 0) {
        float hk[KK], z[KK], m = -1e30f, den = 0.f;
        #pragma unroll
        for (int k = 0; k < KK; ++k)
            hk[k] = fmaxf(red[k * 2] + red[k * 2 + 1] + fc1_b[k], 0.f);
        #pragma unroll
        for (int k = 0; k < KK; ++k) {
            float t = fc2_b[k];
            #pragma unroll
            for (int j = 0; j < KK; ++j) t += hk[j] * fc2_w[k * KK + j];
            z[k] = t; m = fmaxf(m, t);
        }
        #pragma unroll
        for (int k = 0; k < KK; ++k) { z[k] = expf(z[k] - m); den += z[k]; }
        #pragma unroll
        for (int k = 0; k < KK; ++k) attn[b * KK + k] = z[k] / den;
    }
}

// ---- agg_w (bf16) in layout [b][j][ci][o][c32] + fused agg_b ----
__global__ void aggw_kernel(const float* __restrict__ attn, const float* __restrict__ weight,
                            const float* __restrict__ bias,
                            ushort* __restrict__ aggw, float* __restrict__ agg_b) {
    int idx = blockIdx.x * 256 + threadIdx.x;
    if (idx < BB * 9 * OO * CC) {
        int cc = idx & 31;
        int t1 = idx >> 5;
        int o  = t1 & 127;
        int t2 = t1 >> 7;
        int ci = t2 & 3;
        int t3 = t2 >> 2;
        int j  = t3 % 9;
        int b  = t3 / 9;
        int c  = ci * 32 + cc;
        size_t wi = ((size_t)(o * CC + c)) * 9 + j;
        float s = attn[b*KK + 0] * weight[wi]
                + attn[b*KK + 1] * weight[wi + (size_t)WPLANE]
                + attn[b*KK + 2] * weight[wi + (size_t)2*WPLANE]
                + attn[b*KK + 3] * weight[wi + (size_t)3*WPLANE];
        __hip_bfloat16 hb = __float2bfloat16(s);
        aggw[idx] = *(ushort*)&hb;
    }
    if (blockIdx.x < 16) {
        int i = blockIdx.x * 256 + threadIdx.x;   // 0..4095
        int b = i >> 7, o = i & 127;
        float s = 0.f;
        #pragma unroll
        for (int k = 0; k < KK; ++k) s += attn[b*KK + k] * bias[k*OO + o];
        agg_b[i] = s;
    }
}

// ================= shared conv body (device inline) =================
// Computes acc[4][7] for this thread (R9 geometry: 2 o-half x 2 p-half waves,
// M_wave=64, 6-row tile). DBUF selects double- (fallback) or single-buffered
// (coop, halves LDS for the runtime's co-residency check).
template <bool DBUF>
static __device__ __forceinline__ void conv_body(
        const ushort* __restrict__ xbf, const ushort* __restrict__ aggw,
        const ushort* __restrict__ zpage, ushort* xs,
        int b, int h0, int wg, int wy, int cf, int kg, int wid, int lane,
        f32x4 (&acc)[4][7]) {
    // staging: q = wid+4k (q<22); LDS slot un = q*64+lane receives global unit
    // u = un ^ ((un>>3)&7) (involution). Halo/pad -> zpage.
    const ushort* gp[6]; int gstep[6];
    #pragma unroll
    for (int k = 0; k < 6; ++k) {
        int q = wid + 4 * k;
        int un = q * 64 + lane;
        int u = un ^ ((un >> 3) & 7);
        int pos = u >> 2, quad = u & 3;
        int row = pos / 58, col = pos - row * 58;
        int gh = h0 - 1 + row, gw = col - 1;
        bool valid = (pos < NPOS) && (gh >= 0) && (gh < HH) && (gw >= 0) && (gw < WW);
        gp[k] = valid ? (xbf + ((size_t)((b * HH + gh) * WW + gw)) * CC + quad * 8) : zpage;
        gstep[k] = valid ? 32 : 0;
    }

    int blin[7];
    #pragma unroll
    for (int nf = 0; nf < 7; ++nf) {
        int p = wy * 112 + nf * 16 + cf;
        int r = p / 56, w = p - r * 56;
        blin[nf] = (((r + 1) * 58 + (w + 1)) << 6) + kg * 16;
    }

    const ushort* Ab = aggw + ((size_t)b * 36) * 4096 + (size_t)(wg * 64 + cf) * 32 + kg * 8;
    #define ALOAD(mf_, j_, ci_) (*(const short8v*)(Ab + (size_t)((j_) * 4 + (ci_)) * 4096 + (mf_) * 512))

    short8v pa[4];
    #pragma unroll
    for (int mf = 0; mf < 4; ++mf) pa[mf] = ALOAD(mf, 0, 0);

    // prologue: stage chunk 0 into buf 0
    #pragma unroll
    for (int k = 0; k < 6; ++k) {
        int q = wid + 4 * k;
        if (q < 22) { gload16(gp[k], (char*)xs + q * 1024); gp[k] += gstep[k]; }
    }
    __syncthreads();

    int cur = 0;
    for (int ci = 0; ci < 4; ++ci) {
        if (DBUF && ci < 3) {
            char* base = (char*)xs + (cur ^ 1) * BUFB;
            #pragma unroll
            for (int k = 0; k < 6; ++k) {
                int q = wid + 4 * k;
                if (q < 22) { gload16(gp[k], base + q * 1024); gp[k] += gstep[k]; }
            }
        }
        const char* xbuf = (const char*)xs + (DBUF ? cur * BUFB : 0);

        short8v bfc[7], bfn[7];
        #pragma unroll
        for (int nf = 0; nf < 7; ++nf) {
            int lin = blin[nf] + (-58 - 1) * 64;
            int swz = lin ^ ((lin >> 3) & 0x70);
            bfc[nf] = *(const short8v*)(xbuf + swz);
        }
        #pragma unroll
        for (int j = 0; j < 9; ++j) {
            if (j < 8) {
                const int toff = (((j+1)/3 - 1) * 58 + ((j+1)%3 - 1)) * 64;
                #pragma unroll
                for (int nf = 0; nf < 7; ++nf) {
                    int lin = blin[nf] + toff;
                    int swz = lin ^ ((lin >> 3) & 0x70);
                    bfn[nf] = *(const short8v*)(xbuf + swz);
                }
            }
            short8v ca[4];
            #pragma unroll
            for (int mf = 0; mf < 4; ++mf) ca[mf] = pa[mf];
            if (j < 8) {
                #pragma unroll
                for (int mf = 0; mf < 4; ++mf) pa[mf] = ALOAD(mf, j + 1, ci);
            } else if (ci < 3) {
                #pragma unroll
                for (int mf = 0; mf < 4; ++mf) pa[mf] = ALOAD(mf, 0, ci + 1);
            }
            #pragma unroll
            for (int nf = 0; nf < 7; ++nf) {
                #pragma unroll
                for (int mf = 0; mf < 4; ++mf)
                    acc[mf][nf] = __builtin_amdgcn_mfma_f32_16x16x32_bf16(ca[mf], bfc[nf], acc[mf][nf], 0, 0, 0);
            }
            if (j < 8) {
                #pragma unroll
                for (int nf = 0; nf < 7; ++nf) bfc[nf] = bfn[nf];
            }
        }
        if (ci < 3) {
            if (!DBUF) {
                // single-buffer: stage next chunk after compute, extra barrier
                __syncthreads();
                #pragma unroll
                for (int k = 0; k < 6; ++k) {
                    int q = wid + 4 * k;
                    if (q < 22) { gload16(gp[k], (char*)xs + q * 1024); gp[k] += gstep[k]; }
                }
            }
            __syncthreads();
            cur ^= 1;
        }
    }
    #undef ALOAD
}

// ---- fallback conv (R9): dbuf, writes out + stats partials ----
__launch_bounds__(256, 2)
__global__ void conv_kernel(const ushort* __restrict__ xbf, const ushort* __restrict__ aggw,
                            const float* __restrict__ agg_b, const ushort* __restrict__ zpage,
                            float* __restrict__ out,
                            float* __restrict__ psum, float* __restrict__ psumsq) {
    const int lid  = blockIdx.x;
    const int gwid = (lid & 7) * 56 + (lid >> 3);   // XCD swizzle
    const int b = gwid / 14;
    const int t = gwid - b * 14;
    const int h0 = t * 4;
    __shared__ ushort xs[2 * BUFB / 2];   // 45056 B

    const int tid  = threadIdx.x;
    const int lane = tid & 63;
    const int wid  = tid >> 6;
    const int wg = wid & 1, wy = wid >> 1;
    const int cf = lane & 15, kg = lane >> 4;

    f32x4 acc[4][7];
    #pragma unroll
    for (int mf = 0; mf < 4; ++mf)
        #pragma unroll
        for (int nf = 0; nf < 7; ++nf) acc[mf][nf] = (f32x4){0.f, 0.f, 0.f, 0.f};

    conv_body<true>(xbf, aggw, zpage, xs, b, h0, wg, wy, cf, kg, wid, lane, acc);

    #pragma unroll
    for (int mf = 0; mf < 4; ++mf) {
        #pragma unroll
        for (int i = 0; i < 4; ++i) {
            const int o = wg * 64 + mf * 16 + kg * 4 + i;
            const float ab = agg_b[b * OO + o];
            float* op = out + ((size_t)(b * OO + o)) * HW;
            float s = 0.f, s2 = 0.f;
            #pragma unroll
            for (int nf = 0; nf < 7; ++nf) {
                int p = wy * 112 + nf * 16 + cf;
                int r = p / 56, w = p - r * 56;
                float v = acc[mf][nf][i] + ab;
                op[(h0 + r) * WW + w] = v;
                s += v; s2 += v * v;
            }
            s  += __shfl_xor(s, 1, 64);  s  += __shfl_xor(s, 2, 64);
            s  += __shfl_xor(s, 4, 64);  s  += __shfl_xor(s, 8, 64);
            s2 += __shfl_xor(s2, 1, 64); s2 += __shfl_xor(s2, 2, 64);
            s2 += __shfl_xor(s2, 4, 64); s2 += __shfl_xor(s2, 8, 64);
            if (cf == 0) {
                int row = (b * 14 + t) * 2 + wy;
                psum[row * OO + o]   = s;
                psumsq[row * OO + o] = s2;
            }
        }
    }
}

// ---- cooperative conv + fused BN + ReLU (single-buffer LDS: 22.5 KB) ----
__launch_bounds__(256, 2)
__global__ void conv_bn_kernel(const ushort* __restrict__ xbf, const ushort* __restrict__ aggw,
                               const float* __restrict__ agg_b, const ushort* __restrict__ zpage,
                               float* __restrict__ out,
                               float* __restrict__ psum, float* __restrict__ psumsq,
                               float* __restrict__ sums, float* __restrict__ sumsq,
                               const float* __restrict__ gamma, const float* __restrict__ beta) {
    const int lid  = blockIdx.x;
    const int gwid = (lid & 7) * 56 + (lid >> 3);   // XCD swizzle
    const int b = gwid / 14;
    const int t = gwid - b * 14;
    const int h0 = t * 4;
    __shared__ ushort xs[BUFB / 2];       // 22528 B (single buffer)

    const int tid  = threadIdx.x;
    const int lane = tid & 63;
    const int wid  = tid >> 6;
    const int wg = wid & 1, wy = wid >> 1;
    const int cf = lane & 15, kg = lane >> 4;

    f32x4 acc[4][7];
    #pragma unroll
    for (int mf = 0; mf < 4; ++mf)
        #pragma unroll
        for (int nf = 0; nf < 7; ++nf) acc[mf][nf] = (f32x4){0.f, 0.f, 0.f, 0.f};

    conv_body<false>(xbf, aggw, zpage, xs, b, h0, wg, wy, cf, kg, wid, lane, acc);

    // phase A epilogue: add agg_b into live acc, stats partials
    #pragma unroll
    for (int mf = 0; mf < 4; ++mf) {
        #pragma unroll
        for (int i = 0; i < 4; ++i) {
            const int o = wg * 64 + mf * 16 + kg * 4 + i;
            const float ab = agg_b[b * OO + o];
            float s = 0.f, s2 = 0.f;
            #pragma unroll
            for (int nf = 0; nf < 7; ++nf) {
                float v = acc[mf][nf][i] + ab;
                acc[mf][nf][i] = v;
                s += v; s2 += v * v;
            }
            s  += __shfl_xor(s, 1, 64);  s  += __shfl_xor(s, 2, 64);
            s  += __shfl_xor(s, 4, 64);  s  += __shfl_xor(s, 8, 64);
            s2 += __shfl_xor(s2, 1, 64); s2 += __shfl_xor(s2, 2, 64);
            s2 += __shfl_xor(s2, 4, 64); s2 += __shfl_xor(s2, 8, 64);
            if (cf == 0) {
                int row = (b * 14 + t) * 2 + wy;
                psum[row * OO + o]   = s;
                psumsq[row * OO + o] = s2;
            }
        }
    }

    cg::grid_group grid = cg::this_grid();
    grid.sync();

    // phase B: blocks 0..127 reduce channel o = lid over 896 rows
    if (lid < 128) {
        const int o = lid;
        float s = 0.f, s2 = 0.f;
        for (int r = tid; r < 896; r += 256) {
            s  += psum[r * OO + o];
            s2 += psumsq[r * OO + o];
        }
        for (int off = 32; off > 0; off >>= 1) {
            s  += __shfl_down(s, off, 64);
            s2 += __shfl_down(s2, off, 64);
        }
        float* red = (float*)xs;
        if (lane == 0) { red[wid] = s; red[8 + wid] = s2; }
        __syncthreads();
        if (tid == 0) {
            sums[o]  = red[0] + red[1] + red[2] + red[3];
            sumsq[o] = red[8] + red[9] + red[10] + red[11];
        }
    }
    grid.sync();

    // phase C: normalize live registers, ReLU, single out write
    float* sl = (float*)xs;
    if (tid < 128) { sl[tid] = sums[tid]; sl[128 + tid] = sumsq[tid]; }
    __syncthreads();

    const float invN = 1.0f / (float)(BB * HW);
    #pragma unroll
    for (int mf = 0; mf < 4; ++mf) {
        #pragma unroll
        for (int i = 0; i < 4; ++i) {
            const int o = wg * 64 + mf * 16 + kg * 4 + i;
            float mean = sl[o] * invN;
            float var  = sl[128 + o] * invN - mean * mean;
            float inv  = rsqrtf(var + EPSV);
            float g  = gamma[o] * inv;
            float bt = beta[o] - mean * g;
            float* op = out + ((size_t)(b * OO + o)) * HW;
            #pragma unroll
            for (int nf = 0; nf < 7; ++nf) {
                int p = wy * 112 + nf * 16 + cf;
                int r = p / 56, w = p - r * 56;
                op[(h0 + r) * WW + w] = fmaxf(acc[mf][nf][i] * g + bt, 0.f);
            }
        }
    }
}

// ---- fallback final stats + BN ----
__global__ void finstats_kernel(const float* __restrict__ psum, const float* __restrict__ psumsq,
                                float* __restrict__ sums, float* __restrict__ sumsq) {
    const int o = blockIdx.x, l = threadIdx.x;   // 64 threads
    float s = 0.f, s2 = 0.f;
    for (int r = l; r < 896; r += 64) { s += psum[r * OO + o]; s2 += psumsq[r * OO + o]; }
    for (int off = 32; off > 0; off >>= 1) {
        s  += __shfl_down(s, off, 64);
        s2 += __shfl_down(s2, off, 64);
    }
    if (l == 0) { sums[o] = s; sumsq[o] = s2; }
}

__global__ void bn_kernel(float* __restrict__ out,
                          const float* __restrict__ sums, const float* __restrict__ sumsq,
                          const float* __restrict__ gamma, const float* __restrict__ beta) {
    const float invN = 1.0f / (float)(BB * HW);
    const int total4 = BB * OO * HW / 4;
    for (int i = blockIdx.x * blockDim.x + threadIdx.x; i < total4; i += gridDim.x * blockDim.x) {
        int o = (i / (HW/4)) % OO;
        float mean = sums[o] * invN;
        float var  = sumsq[o] * invN - mean*mean;
        float inv  = rsqrtf(var + EPSV);
        float g  = gamma[o] * inv;
        float bt = beta[o] - mean * g;
        float4 v = ((float4*)out)[i];
        v.x = fmaxf(v.x*g + bt, 0.f);
        v.y = fmaxf(v.y*g + bt, 0.f);
        v.z = fmaxf(v.z*g + bt, 0.f);
        v.w = fmaxf(v.w*g + bt, 0.f);
        ((float4*)out)[i] = v;
    }
}

extern "C" void kernel_launch(void* const* d_in, const int* in_sizes, int n_in,
                              void* d_out, int out_size, void* d_ws, size_t ws_size,
                              hipStream_t stream) {
    const float* x      = (const float*)d_in[0];
    const float* fc1_w  = (const float*)d_in[1];
    const float* fc1_b  = (const float*)d_in[2];
    const float* fc2_w  = (const float*)d_in[3];
    const float* fc2_b  = (const float*)d_in[4];
    const float* weight = (const float*)d_in[5];
    const float* bias   = (const float*)d_in[6];
    const float* gamma  = (const float*)d_in[7];
    const float* beta   = (const float*)d_in[8];
    float* out = (float*)d_out;

    const size_t XBF_ELEMS  = (size_t)BB * HW * CC;        // 12,845,056
    const size_t AGGW_ELEMS = (size_t)BB * 9 * OO * CC;    //  4,718,592
    ushort* xbf  = (ushort*)d_ws;
    ushort* aggw = xbf + XBF_ELEMS;
    float*  wsf  = (float*)(aggw + AGGW_ELEMS);
    float* pooledp = wsf;                    // 229376
    float* attn    = pooledp + 229376;       // 128
    float* agg_b   = attn + 128;             // 4096
    float* psum    = agg_b + 4096;           // 114688 (896*128)
    float* psumsq  = psum + 114688;          // 114688
    float* sums    = psumsq + 114688;        // 128
    float* sumsq   = sums + 128;             // 128
    ushort* zpage  = (ushort*)(sumsq + 128); // 32 shorts, zeroed by convert_pool

    convert_pool_kernel<<<dim3(HH, BB), 256, 0, stream>>>(x, xbf, pooledp, zpage);
    attn_kernel<<<BB, 128, 0, stream>>>(pooledp, fc1_w, fc1_b, fc2_w, fc2_b, attn);
    aggw_kernel<<<(int)((AGGW_ELEMS + 255)/256), 256, 0, stream>>>(attn, weight, bias, aggw, agg_b);

    void* cargs[] = { (void*)&xbf, (void*)&aggw, (void*)&agg_b, (void*)&zpage,
                      (void*)&out, (void*)&psum, (void*)&psumsq,
                      (void*)&sums, (void*)&sumsq, (void*)&gamma, (void*)&beta };
    hipError_t cerr = hipLaunchCooperativeKernel((const void*)conv_bn_kernel,
                                                 dim3(448), dim3(256), cargs, 0, stream);
    if (cerr != hipSuccess) {
        (void)hipGetLastError();   // clear sticky error; fall back to split path
        conv_kernel<<<dim3(448), 256, 0, stream>>>(xbf, aggw, agg_b, zpage, out, psum, psumsq);
        finstats_kernel<<<OO, 64, 0, stream>>>(psum, psumsq, sums, sumsq);
        bn_kernel<<<2048, 256, 0, stream>>>(out, sums, sumsq, gamma, beta);
    }
}

// Round 14
// 99.766 us; speedup vs baseline: 2.4804x; 2.4804x over previous
//
#include <hip/hip_runtime.h>
#include <hip/hip_bf16.h>

#define BB 32
#define CC 128
#define OO 128
#define HH 56
#define WW 56
#define KK 4
#define HW 3136
#define WPLANE 147456
#define EPSV 1e-5f

#define NPOS 348                  // 6 rows x 58 cols staged positions
#define BUFB 22528                // bytes per LDS buffer = 1408 units x 16B (incl pad)

typedef __attribute__((ext_vector_type(8))) short short8v;
typedef __attribute__((ext_vector_type(4))) float f32x4;

static __device__ __forceinline__ void gload16(const void* g, void* l) {
    __builtin_amdgcn_global_load_lds((const __attribute__((address_space(1))) void*)g,
                                     (__attribute__((address_space(3))) void*)l, 16, 0, 0);
}

// ---- convert x -> bf16 channel-last [b][h][w][c], + per-(b,h,c) row sums ----
__global__ void convert_pool_kernel(const float* __restrict__ x,
                                    ushort* __restrict__ xbf,
                                    float* __restrict__ pooledp,
                                    ushort* __restrict__ zpage) {
    const int h = blockIdx.x, b = blockIdx.y;
    if (h == 0 && b == 0 && threadIdx.x < 32) zpage[threadIdx.x] = 0;
    __shared__ float4 xl4[1792];               // [c][w4] swizzled, 28672 B
    const float* xp = x + (size_t)(b * CC) * HW + h * WW;

    #pragma unroll
    for (int k = 0; k < 7; ++k) {
        int u = threadIdx.x + k * 256;
        int c = u / 14, w4 = u - c * 14;
        float4 v = *(const float4*)(xp + (size_t)c * HW + w4 * 4);
        xl4[u ^ ((c >> 3) & 7)] = v;
    }
    __syncthreads();

    const float* xf = (const float*)xl4;
    #pragma unroll
    for (int k = 0; k < 4; ++k) {
        int v = threadIdx.x + k * 256;
        if (v < 896) {
            int w = v >> 4, c8 = v & 15;
            int w4 = w >> 2, wo = w & 3;
            short8v res;
            #pragma unroll
            for (int j = 0; j < 8; ++j) {
                int c = c8 * 8 + j;
                int su = (c * 14 + w4) ^ (c8 & 7);
                __hip_bfloat16 hb = __float2bfloat16(xf[su * 4 + wo]);
                res[j] = *(short*)&hb;
            }
            *(short8v*)(xbf + ((size_t)((b * HH + h) * WW + w)) * CC + c8 * 8) = res;
        }
    }

    if (threadIdx.x < 128) {
        int c = threadIdx.x;
        float s = 0.f;
        #pragma unroll
        for (int w4 = 0; w4 < 14; ++w4) {
            float4 v = xl4[(c * 14 + w4) ^ ((c >> 3) & 7)];
            s += v.x + v.y + v.z + v.w;
        }
        pooledp[((size_t)(b * HH + h)) * CC + c] = s;
    }
}

// ---- attention: reduce pooled partials + tiny MLP + softmax. block per b ----
__global__ void attn_kernel(const float* __restrict__ pooledp,
                            const float* __restrict__ fc1_w, const float* __restrict__ fc1_b,
                            const float* __restrict__ fc2_w, const float* __restrict__ fc2_b,
                            float* __restrict__ attn) {
    const int b = blockIdx.x, c = threadIdx.x;      // 128 threads
    float s = 0.f;
    for (int h = 0; h < HH; ++h) s += pooledp[((size_t)(b * HH + h)) * CC + c];
    const float pc = s * (1.0f / HW);
    __shared__ float red[8];
    const int lane = c & 63, wid = c >> 6;
    #pragma unroll
    for (int k = 0; k < KK; ++k) {
        float v = pc * fc1_w[k * CC + c];
        for (int off = 32; off > 0; off >>= 1) v += __shfl_down(v, off, 64);
        if (lane == 0) red[k * 2 + wid] = v;
    }
    __syncthreads();
    if (c == 0) {
        float hk[KK], z[KK], m = -1e30f, den = 0.f;
        #pragma unroll
        for (int k = 0; k < KK; ++k)
            hk[k] = fmaxf(red[k * 2] + red[k * 2 + 1] + fc1_b[k], 0.f);
        #pragma unroll
        for (int k = 0; k < KK; ++k) {
            float t = fc2_b[k];
            #pragma unroll
            for (int j = 0; j < KK; ++j) t += hk[j] * fc2_w[k * KK + j];
            z[k] = t; m = fmaxf(m, t);
        }
        #pragma unroll
        for (int k = 0; k < KK; ++k) { z[k] = expf(z[k] - m); den += z[k]; }
        #pragma unroll
        for (int k = 0; k < KK; ++k) attn[b * KK + k] = z[k] / den;
    }
}

// ---- agg_w (bf16) in layout [b][j][ci][o][c32] + fused agg_b ----
__global__ void aggw_kernel(const float* __restrict__ attn, const float* __restrict__ weight,
                            const float* __restrict__ bias,
                            ushort* __restrict__ aggw, float* __restrict__ agg_b) {
    int idx = blockIdx.x * 256 + threadIdx.x;
    if (idx < BB * 9 * OO * CC) {
        int cc = idx & 31;
        int t1 = idx >> 5;
        int o  = t1 & 127;
        int t2 = t1 >> 7;
        int ci = t2 & 3;
        int t3 = t2 >> 2;
        int j  = t3 % 9;
        int b  = t3 / 9;
        int c  = ci * 32 + cc;
        size_t wi = ((size_t)(o * CC + c)) * 9 + j;
        float s = attn[b*KK + 0] * weight[wi]
                + attn[b*KK + 1] * weight[wi + (size_t)WPLANE]
                + attn[b*KK + 2] * weight[wi + (size_t)2*WPLANE]
                + attn[b*KK + 3] * weight[wi + (size_t)3*WPLANE];
        __hip_bfloat16 hb = __float2bfloat16(s);
        aggw[idx] = *(ushort*)&hb;
    }
    if (blockIdx.x < 16) {
        int i = blockIdx.x * 256 + threadIdx.x;   // 0..4095
        int b = i >> 7, o = i & 127;
        float s = 0.f;
        #pragma unroll
        for (int k = 0; k < KK; ++k) s += attn[b*KK + k] * bias[k*OO + o];
        agg_b[i] = s;
    }
}

// ================= shared conv body (R9 geometry, dbuf) =================
static __device__ __forceinline__ void conv_body(
        const ushort* __restrict__ xbf, const ushort* __restrict__ aggw,
        const ushort* __restrict__ zpage, ushort* xs,
        int b, int h0, int wg, int wy, int cf, int kg, int wid, int lane,
        f32x4 (&acc)[4][7]) {
    const ushort* gp[6]; int gstep[6];
    #pragma unroll
    for (int k = 0; k < 6; ++k) {
        int q = wid + 4 * k;
        int un = q * 64 + lane;
        int u = un ^ ((un >> 3) & 7);
        int pos = u >> 2, quad = u & 3;
        int row = pos / 58, col = pos - row * 58;
        int gh = h0 - 1 + row, gw = col - 1;
        bool valid = (pos < NPOS) && (gh >= 0) && (gh < HH) && (gw >= 0) && (gw < WW);
        gp[k] = valid ? (xbf + ((size_t)((b * HH + gh) * WW + gw)) * CC + quad * 8) : zpage;
        gstep[k] = valid ? 32 : 0;
    }

    int blin[7];
    #pragma unroll
    for (int nf = 0; nf < 7; ++nf) {
        int p = wy * 112 + nf * 16 + cf;
        int r = p / 56, w = p - r * 56;
        blin[nf] = (((r + 1) * 58 + (w + 1)) << 6) + kg * 16;
    }

    const ushort* Ab = aggw + ((size_t)b * 36) * 4096 + (size_t)(wg * 64 + cf) * 32 + kg * 8;
    #define ALOAD(mf_, j_, ci_) (*(const short8v*)(Ab + (size_t)((j_) * 4 + (ci_)) * 4096 + (mf_) * 512))

    short8v pa[4];
    #pragma unroll
    for (int mf = 0; mf < 4; ++mf) pa[mf] = ALOAD(mf, 0, 0);

    #pragma unroll
    for (int k = 0; k < 6; ++k) {
        int q = wid + 4 * k;
        if (q < 22) { gload16(gp[k], (char*)xs + q * 1024); gp[k] += gstep[k]; }
    }
    __syncthreads();

    int cur = 0;
    for (int ci = 0; ci < 4; ++ci) {
        if (ci < 3) {
            char* base = (char*)xs + (cur ^ 1) * BUFB;
            #pragma unroll
            for (int k = 0; k < 6; ++k) {
                int q = wid + 4 * k;
                if (q < 22) { gload16(gp[k], base + q * 1024); gp[k] += gstep[k]; }
            }
        }
        const char* xbuf = (const char*)xs + cur * BUFB;

        short8v bfc[7], bfn[7];
        #pragma unroll
        for (int nf = 0; nf < 7; ++nf) {
            int lin = blin[nf] + (-58 - 1) * 64;
            int swz = lin ^ ((lin >> 3) & 0x70);
            bfc[nf] = *(const short8v*)(xbuf + swz);
        }
        #pragma unroll
        for (int j = 0; j < 9; ++j) {
            if (j < 8) {
                const int toff = (((j+1)/3 - 1) * 58 + ((j+1)%3 - 1)) * 64;
                #pragma unroll
                for (int nf = 0; nf < 7; ++nf) {
                    int lin = blin[nf] + toff;
                    int swz = lin ^ ((lin >> 3) & 0x70);
                    bfn[nf] = *(const short8v*)(xbuf + swz);
                }
            }
            short8v ca[4];
            #pragma unroll
            for (int mf = 0; mf < 4; ++mf) ca[mf] = pa[mf];
            if (j < 8) {
                #pragma unroll
                for (int mf = 0; mf < 4; ++mf) pa[mf] = ALOAD(mf, j + 1, ci);
            } else if (ci < 3) {
                #pragma unroll
                for (int mf = 0; mf < 4; ++mf) pa[mf] = ALOAD(mf, 0, ci + 1);
            }
            #pragma unroll
            for (int nf = 0; nf < 7; ++nf) {
                #pragma unroll
                for (int mf = 0; mf < 4; ++mf)
                    acc[mf][nf] = __builtin_amdgcn_mfma_f32_16x16x32_bf16(ca[mf], bfc[nf], acc[mf][nf], 0, 0, 0);
            }
            if (j < 8) {
                #pragma unroll
                for (int nf = 0; nf < 7; ++nf) bfc[nf] = bfn[nf];
            }
        }
        if (ci < 3) __syncthreads();
        cur ^= 1;
    }
    #undef ALOAD
}

// ---- conv, bf16 output to ws (BF16OUT) or fp32 to d_out ----
template <bool BF16OUT>
__launch_bounds__(256, 2)
__global__ void conv_kernel(const ushort* __restrict__ xbf, const ushort* __restrict__ aggw,
                            const float* __restrict__ agg_b, const ushort* __restrict__ zpage,
                            void* __restrict__ outv,
                            float* __restrict__ psum, float* __restrict__ psumsq) {
    const int lid  = blockIdx.x;
    const int gwid = (lid & 7) * 56 + (lid >> 3);   // XCD swizzle
    const int b = gwid / 14;
    const int t = gwid - b * 14;
    const int h0 = t * 4;
    __shared__ ushort xs[2 * BUFB / 2];   // 45056 B

    const int tid  = threadIdx.x;
    const int lane = tid & 63;
    const int wid  = tid >> 6;
    const int wg = wid & 1, wy = wid >> 1;
    const int cf = lane & 15, kg = lane >> 4;

    f32x4 acc[4][7];
    #pragma unroll
    for (int mf = 0; mf < 4; ++mf)
        #pragma unroll
        for (int nf = 0; nf < 7; ++nf) acc[mf][nf] = (f32x4){0.f, 0.f, 0.f, 0.f};

    conv_body(xbf, aggw, zpage, xs, b, h0, wg, wy, cf, kg, wid, lane, acc);

    #pragma unroll
    for (int mf = 0; mf < 4; ++mf) {
        #pragma unroll
        for (int i = 0; i < 4; ++i) {
            const int o = wg * 64 + mf * 16 + kg * 4 + i;
            const float ab = agg_b[b * OO + o];
            const size_t obase = ((size_t)(b * OO + o)) * HW;
            float s = 0.f, s2 = 0.f;
            #pragma unroll
            for (int nf = 0; nf < 7; ++nf) {
                int p = wy * 112 + nf * 16 + cf;
                int r = p / 56, w = p - r * 56;
                float v = acc[mf][nf][i] + ab;
                if (BF16OUT) {
                    __hip_bfloat16 hb = __float2bfloat16(v);
                    ((ushort*)outv)[obase + (h0 + r) * WW + w] = *(ushort*)&hb;
                } else {
                    ((float*)outv)[obase + (h0 + r) * WW + w] = v;
                }
                s += v; s2 += v * v;
            }
            s  += __shfl_xor(s, 1, 64);  s  += __shfl_xor(s, 2, 64);
            s  += __shfl_xor(s, 4, 64);  s  += __shfl_xor(s, 8, 64);
            s2 += __shfl_xor(s2, 1, 64); s2 += __shfl_xor(s2, 2, 64);
            s2 += __shfl_xor(s2, 4, 64); s2 += __shfl_xor(s2, 8, 64);
            if (cf == 0) {
                int row = (b * 14 + t) * 2 + wy;
                psum[row * OO + o]   = s;
                psumsq[row * OO + o] = s2;
            }
        }
    }
}

// ---- final stats: one block per channel ----
__global__ void finstats_kernel(const float* __restrict__ psum, const float* __restrict__ psumsq,
                                float* __restrict__ sums, float* __restrict__ sumsq) {
    const int o = blockIdx.x, l = threadIdx.x;   // 64 threads
    float s = 0.f, s2 = 0.f;
    for (int r = l; r < 896; r += 64) { s += psum[r * OO + o]; s2 += psumsq[r * OO + o]; }
    for (int off = 32; off > 0; off >>= 1) {
        s  += __shfl_down(s, off, 64);
        s2 += __shfl_down(s2, off, 64);
    }
    if (l == 0) { sums[o] = s; sumsq[o] = s2; }
}

// ---- BN + ReLU: bf16 conv output -> fp32 out ----
__global__ void bn_bf16_kernel(const ushort* __restrict__ convout, float* __restrict__ out,
                               const float* __restrict__ sums, const float* __restrict__ sumsq,
                               const float* __restrict__ gamma, const float* __restrict__ beta) {
    const float invN = 1.0f / (float)(BB * HW);
    const int total8 = BB * OO * HW / 8;         // 1,605,632 ushort8 units
    for (int i = blockIdx.x * blockDim.x + threadIdx.x; i < total8; i += gridDim.x * blockDim.x) {
        int o = (i / (HW/8)) % OO;               // HW/8 = 392
        float mean = sums[o] * invN;
        float var  = sumsq[o] * invN - mean*mean;
        float inv  = rsqrtf(var + EPSV);
        float g  = gamma[o] * inv;
        float bt = beta[o] - mean * g;
        short8v v = *(const short8v*)(convout + (size_t)i * 8);
        float4 lo, hi;
        #pragma unroll
        for (int j = 0; j < 4; ++j) {
            ushort u = (ushort)v[j];
            float f = __bfloat162float(*(__hip_bfloat16*)&u);
            ((float*)&lo)[j] = fmaxf(f * g + bt, 0.f);
        }
        #pragma unroll
        for (int j = 0; j < 4; ++j) {
            ushort u = (ushort)v[4 + j];
            float f = __bfloat162float(*(__hip_bfloat16*)&u);
            ((float*)&hi)[j] = fmaxf(f * g + bt, 0.f);
        }
        ((float4*)out)[i * 2]     = lo;
        ((float4*)out)[i * 2 + 1] = hi;
    }
}

// ---- BN + ReLU in place (fp32 fallback) ----
__global__ void bn_kernel(float* __restrict__ out,
                          const float* __restrict__ sums, const float* __restrict__ sumsq,
                          const float* __restrict__ gamma, const float* __restrict__ beta) {
    const float invN = 1.0f / (float)(BB * HW);
    const int total4 = BB * OO * HW / 4;
    for (int i = blockIdx.x * blockDim.x + threadIdx.x; i < total4; i += gridDim.x * blockDim.x) {
        int o = (i / (HW/4)) % OO;
        float mean = sums[o] * invN;
        float var  = sumsq[o] * invN - mean*mean;
        float inv  = rsqrtf(var + EPSV);
        float g  = gamma[o] * inv;
        float bt = beta[o] - mean * g;
        float4 v = ((float4*)out)[i];
        v.x = fmaxf(v.x*g + bt, 0.f);
        v.y = fmaxf(v.y*g + bt, 0.f);
        v.z = fmaxf(v.z*g + bt, 0.f);
        v.w = fmaxf(v.w*g + bt, 0.f);
        ((float4*)out)[i] = v;
    }
}

extern "C" void kernel_launch(void* const* d_in, const int* in_sizes, int n_in,
                              void* d_out, int out_size, void* d_ws, size_t ws_size,
                              hipStream_t stream) {
    const float* x      = (const float*)d_in[0];
    const float* fc1_w  = (const float*)d_in[1];
    const float* fc1_b  = (const float*)d_in[2];
    const float* fc2_w  = (const float*)d_in[3];
    const float* fc2_b  = (const float*)d_in[4];
    const float* weight = (const float*)d_in[5];
    const float* bias   = (const float*)d_in[6];
    const float* gamma  = (const float*)d_in[7];
    const float* beta   = (const float*)d_in[8];
    float* out = (float*)d_out;

    const size_t XBF_ELEMS  = (size_t)BB * HW * CC;        // 12,845,056
    const size_t AGGW_ELEMS = (size_t)BB * 9 * OO * CC;    //  4,718,592
    const size_t OUT_ELEMS  = (size_t)BB * OO * HW;        // 12,845,056
    ushort* xbf  = (ushort*)d_ws;
    ushort* aggw = xbf + XBF_ELEMS;
    float*  wsf  = (float*)(aggw + AGGW_ELEMS);
    float* pooledp = wsf;                    // 229376
    float* attn    = pooledp + 229376;       // 128
    float* agg_b   = attn + 128;             // 4096
    float* psum    = agg_b + 4096;           // 114688 (896*128)
    float* psumsq  = psum + 114688;          // 114688
    float* sums    = psumsq + 114688;        // 128
    float* sumsq   = sums + 128;             // 128
    ushort* zpage  = (ushort*)(sumsq + 128); // 32 shorts
    ushort* convout = (ushort*)(zpage + 32); // bf16 conv output (25.7 MB) if ws allows

    const size_t need = (size_t)((char*)(convout + OUT_ELEMS) - (char*)d_ws);
    const bool bf16path = ws_size >= need;

    convert_pool_kernel<<<dim3(HH, BB), 256, 0, stream>>>(x, xbf, pooledp, zpage);
    attn_kernel<<<BB, 128, 0, stream>>>(pooledp, fc1_w, fc1_b, fc2_w, fc2_b, attn);
    aggw_kernel<<<(int)((AGGW_ELEMS + 255)/256), 256, 0, stream>>>(attn, weight, bias, aggw, agg_b);

    if (bf16path) {
        conv_kernel<true><<<dim3(448), 256, 0, stream>>>(xbf, aggw, agg_b, zpage,
                                                         (void*)convout, psum, psumsq);
        finstats_kernel<<<OO, 64, 0, stream>>>(psum, psumsq, sums, sumsq);
        bn_bf16_kernel<<<2048, 256, 0, stream>>>(convout, out, sums, sumsq, gamma, beta);
    } else {
        conv_kernel<false><<<dim3(448), 256, 0, stream>>>(xbf, aggw, agg_b, zpage,
                                                          (void*)out, psum, psumsq);
        finstats_kernel<<<OO, 64, 0, stream>>>(psum, psumsq, sums, sumsq);
        bn_kernel<<<2048, 256, 0, stream>>>(out, sums, sumsq, gamma, beta);
    }
}